// Round 6
// baseline (225.207 us; speedup 1.0000x reference)
//
#include <hip/hip_runtime.h>

typedef _Float16 f16x8 __attribute__((ext_vector_type(8)));
typedef _Float16 f16x4 __attribute__((ext_vector_type(4)));
typedef float    f32x4 __attribute__((ext_vector_type(4)));

static constexpr int BATCH = 32;
static constexpr int CDIM  = 256;    // C
static constexpr int HW    = 4096;   // h (= A_H = K of GEMM1)
static constexpr int AW    = 1024;   // A rows (w)
static constexpr int AH    = 4096;   // A cols (h)
static constexpr int BW    = 256;    // B rows (c)
static constexpr int BH    = 512;    // B cols (d)
static constexpr int CAND_CAP = 8192;

// scratch u32 layout
// 0     histA0[4096]   4096  histA1[4096]
// 8192  histB0[4096]   12288 histB1[4096]
// 16384 selA[8]  ([3]=target2 [4]=vcut [5]=cutIdx [6]=candCount)
// 16392 selB[8]
// 16400 candBitsA[8192]  24592 candIdxA[8192]
// 32784 candBitsB[8192]  40976 candIdxB[8192]
static constexpr int MEMSET_U32 = 16400;

__device__ __forceinline__ void gload16(const void* g, void* l) {
    __builtin_amdgcn_global_load_lds((const __attribute__((address_space(1))) void*)g,
                                     (__attribute__((address_space(3))) void*)l, 16, 0, 0);
}

// every block computes the same select result from a global 4096-bin histogram.
__device__ void select_bin_inline(const unsigned* __restrict__ hist, unsigned target,
                                  unsigned* shp /*[256]*/, unsigned* res /*[2]*/) {
    const int t = threadIdx.x;
    unsigned sum = 0;
    #pragma unroll
    for (int k = 0; k < 16; ++k) sum += hist[t * 16 + k];
    shp[t] = sum;
    __syncthreads();
    if (t == 0) {
        unsigned c = 0; int k = 0;
        while (c + shp[k] <= target) { c += shp[k]; ++k; }
        int b = k * 16;
        while (true) { unsigned h = hist[b]; if (target < c + h) break; c += h; ++b; }
        res[0] = (unsigned)b; res[1] = c;
    }
    __syncthreads();
}

// ---------------- pass 0: hist of key>>19 (12 bits), per-wave LDS hist ----------------
__global__ void hist0_kernel(const float* __restrict__ sA, int nA,
                             const float* __restrict__ sB, int nB,
                             unsigned* __restrict__ scratch) {
    __shared__ unsigned lh[4][4096];
    const int y = blockIdx.y;
    const float* s = y ? sB : sA;
    const int n4 = (y ? nB : nA) >> 2;
    unsigned* hist = scratch + (y ? 8192 : 0);
    const int t = threadIdx.x;
    const int wave = t >> 6;
    for (int i = t; i < 4 * 4096; i += 256) ((unsigned*)lh)[i] = 0;
    __syncthreads();
    for (int i = blockIdx.x * 256 + t; i < n4; i += gridDim.x * 256) {
        float4 v = reinterpret_cast<const float4*>(s)[i];
        atomicAdd(&lh[wave][(__float_as_uint(v.x) & 0x7fffffffu) >> 19], 1u);
        atomicAdd(&lh[wave][(__float_as_uint(v.y) & 0x7fffffffu) >> 19], 1u);
        atomicAdd(&lh[wave][(__float_as_uint(v.z) & 0x7fffffffu) >> 19], 1u);
        atomicAdd(&lh[wave][(__float_as_uint(v.w) & 0x7fffffffu) >> 19], 1u);
    }
    __syncthreads();
    for (int b = t; b < 4096; b += 256) {
        unsigned v = lh[0][b] + lh[1][b] + lh[2][b] + lh[3][b];
        if (v) atomicAdd(&hist[b], v);
    }
}

// ---------------- pass 1: inline select0, hist of (key>>7)&4095 among prefix matches ----------------
__global__ void hist1_kernel(const float* __restrict__ sA, int nA, unsigned jA,
                             const float* __restrict__ sB, int nB, unsigned jB,
                             unsigned* __restrict__ scratch) {
    __shared__ unsigned lh[4][4096];
    __shared__ unsigned shp[256];
    __shared__ unsigned res[2];
    const int y = blockIdx.y;
    const float* s = y ? sB : sA;
    const int n4 = (y ? nB : nA) >> 2;
    const unsigned j = y ? jB : jA;
    const unsigned* hist0 = scratch + (y ? 8192 : 0);
    unsigned* hist1 = scratch + 4096 + (y ? 8192 : 0);
    const int t = threadIdx.x;
    const int wave = t >> 6;
    for (int i = t; i < 4 * 4096; i += 256) ((unsigned*)lh)[i] = 0;
    select_bin_inline(hist0, j, shp, res);       // includes syncthreads
    const unsigned bin0 = res[0];
    for (int i = blockIdx.x * 256 + t; i < n4; i += gridDim.x * 256) {
        float4 v = reinterpret_cast<const float4*>(s)[i];
        unsigned k0 = __float_as_uint(v.x) & 0x7fffffffu;
        unsigned k1 = __float_as_uint(v.y) & 0x7fffffffu;
        unsigned k2 = __float_as_uint(v.z) & 0x7fffffffu;
        unsigned k3 = __float_as_uint(v.w) & 0x7fffffffu;
        if ((k0 >> 19) == bin0) atomicAdd(&lh[wave][(k0 >> 7) & 4095], 1u);
        if ((k1 >> 19) == bin0) atomicAdd(&lh[wave][(k1 >> 7) & 4095], 1u);
        if ((k2 >> 19) == bin0) atomicAdd(&lh[wave][(k2 >> 7) & 4095], 1u);
        if ((k3 >> 19) == bin0) atomicAdd(&lh[wave][(k3 >> 7) & 4095], 1u);
    }
    __syncthreads();
    for (int b = t; b < 4096; b += 256) {
        unsigned v = lh[0][b] + lh[1][b] + lh[2][b] + lh[3][b];
        if (v) atomicAdd(&hist1[b], v);
    }
}

// ---------------- extract: inline select0+select1, gather candidates with 24-bit prefix ----------------
__global__ void extract_kernel(const float* __restrict__ sA, int nA, unsigned jA,
                               const float* __restrict__ sB, int nB, unsigned jB,
                               unsigned* __restrict__ scratch) {
    __shared__ unsigned shp[256];
    __shared__ unsigned res0[2], res1[2];
    const int y = blockIdx.y;
    const float* s = y ? sB : sA;
    const int n4 = (y ? nB : nA) >> 2;
    const unsigned j = y ? jB : jA;
    const unsigned* hist0 = scratch + (y ? 8192 : 0);
    const unsigned* hist1 = scratch + 4096 + (y ? 8192 : 0);
    unsigned* sel = scratch + 16384 + y * 8;
    unsigned* candBits = scratch + (y ? 32784 : 16400);
    unsigned* candIdx  = candBits + CAND_CAP;
    const int t = threadIdx.x;
    select_bin_inline(hist0, j, shp, res0);
    select_bin_inline(hist1, j - res0[1], shp, res1);
    const unsigned pref = (res0[0] << 12) | res1[0];
    const unsigned base2 = res0[1] + res1[1];
    if (blockIdx.x == 0 && t == 0) sel[3] = j - base2;   // rank within candidate set
    for (int i = blockIdx.x * 256 + t; i < n4; i += gridDim.x * 256) {
        float4 v = reinterpret_cast<const float4*>(s)[i];
        #pragma unroll
        for (int k = 0; k < 4; ++k) {
            unsigned bits = __float_as_uint(k == 0 ? v.x : k == 1 ? v.y : k == 2 ? v.z : v.w) & 0x7fffffffu;
            if ((bits >> 7) == pref) {
                unsigned p = atomicAdd(&sel[6], 1u);
                if (p < CAND_CAP) { candBits[p] = bits; candIdx[p] = (unsigned)(i * 4 + k); }
            }
        }
    }
}

// ---------------- finalize: exact (value, index)-lexicographic rank among candidates ----------------
__global__ void finalize_kernel(unsigned* __restrict__ scratch) {
    __shared__ unsigned sb[CAND_CAP];
    __shared__ unsigned si[CAND_CAP];
    const int y = blockIdx.y;
    unsigned* sel = scratch + 16384 + y * 8;
    const unsigned* candBits = scratch + (y ? 32784 : 16400);
    const unsigned* candIdx  = candBits + CAND_CAP;
    const int t = threadIdx.x;
    unsigned cnt = sel[6]; if (cnt > CAND_CAP) cnt = CAND_CAP;
    const unsigned target = sel[3];
    for (unsigned c = t; c < cnt; c += 256) { sb[c] = candBits[c]; si[c] = candIdx[c]; }
    __syncthreads();
    for (unsigned c = t; c < cnt; c += 256) {
        unsigned b = sb[c], ix = si[c];
        unsigned r = 0;
        for (unsigned q = 0; q < cnt; ++q)
            r += (sb[q] < b) || (sb[q] == b && si[q] < ix);
        if (r == target) { sel[4] = b; sel[5] = ix; }
    }
}

// ---------------- apply: branchless mask + masked-f16 write + f32 pass-through copy ----------------
__global__ void apply_kernel(const float* __restrict__ sA, const float* __restrict__ wA,
                             _Float16* __restrict__ Am, float* __restrict__ wcopyA,
                             const float* __restrict__ sB, const float* __restrict__ wB,
                             _Float16* __restrict__ BmT, float* __restrict__ wcopyB,
                             int nA, int nB, const unsigned* __restrict__ scratch) {
    const int y = blockIdx.y;
    const float* s = y ? sB : sA;
    const float* w = y ? wB : wA;
    float* wcopy = y ? wcopyB : wcopyA;
    const int n4 = (y ? nB : nA) >> 2;
    const unsigned* sel = scratch + 16384 + y * 8;
    const unsigned vcut = sel[4], cutIdx = sel[5];
    const int t = threadIdx.x;
    for (int i = blockIdx.x * 256 + t; i < n4; i += gridDim.x * 256) {
        float4 sv = reinterpret_cast<const float4*>(s)[i];
        float4 wv = reinterpret_cast<const float4*>(w)[i];
        reinterpret_cast<float4*>(wcopy)[i] = wv;
        unsigned idx0 = (unsigned)i * 4;
        float m[4];
        #pragma unroll
        for (int k = 0; k < 4; ++k) {
            unsigned bits = __float_as_uint(k == 0 ? sv.x : k == 1 ? sv.y : k == 2 ? sv.z : sv.w) & 0x7fffffffu;
            bool keep = (bits > vcut) || (bits == vcut && (idx0 + k) >= cutIdx);
            m[k] = keep ? 1.0f : 0.0f;
        }
        if (!y) {
            f16x4 o = { (_Float16)(wv.x * m[0]), (_Float16)(wv.y * m[1]),
                        (_Float16)(wv.z * m[2]), (_Float16)(wv.w * m[3]) };
            *reinterpret_cast<f16x4*>(Am + idx0) = o;
        } else {
            int c = (int)(idx0 >> 9);           // row of B_ref [256][512]
            int d = (int)(idx0 & 511);
            BmT[(size_t)(d + 0) * BW + c] = (_Float16)(wv.x * m[0]);
            BmT[(size_t)(d + 1) * BW + c] = (_Float16)(wv.y * m[1]);
            BmT[(size_t)(d + 2) * BW + c] = (_Float16)(wv.z * m[2]);
            BmT[(size_t)(d + 3) * BW + c] = (_Float16)(wv.w * m[3]);
        }
    }
}

// ---------------- GEMM1 (merged batch, dbuf 2-phase): temp[b][w][c] = sum_h Am[w][h]*x[(b,c)][h] ----
// A (f16) via global_load_lds (pre-swizzled source, linear dest). x reg-staged f32 -> cvt f16 at
// staging -> swizzled ds_write (issue-early/write-late). Double-buffered: stage(next) issued
// before MFMA(cur); one barrier per iter AFTER compute, so loads fly under MFMA.
__global__ __launch_bounds__(256) void gemm1_kernel(
        const _Float16* __restrict__ Am,   // [1024][4096] f16
        const float* __restrict__ x,       // [8192][4096] f32  ((b,c) major)
        _Float16* __restrict__ temp) {     // [32][1024][256] f16
    __shared__ __align__(16) char lds[65536];   // 2 bufs x (As 16K + Xs 16K)
    const int t = threadIdx.x;
    const int lane = t & 63;
    const int wave = t >> 6;
    const int wm = (wave >> 1) * 64;
    const int wn = (wave & 1) * 64;

    // XCD-local x reuse: XCD k owns bx in [8k,8k+8); all 8 by per bx run on that XCD.
    const int xcd = blockIdx.x & 7;
    const int seq = blockIdx.x >> 3;
    const int bx = xcd * 8 + (seq >> 3);   // N-tile 0..63 (b,c)
    const int by = seq & 7;                // M-tile 0..7  (w)

    // staging decomposition: chunk c = i*256 + t; row = c>>3 (0..127), kk = c&7 (16B chunk)
    const int sRow = t >> 3;               // + i*32
    const int sKk  = t & 7;
    const int aKkSwz = sKk ^ (sRow & 7);   // (i*32+row)&7 == row&7
    const _Float16* aSrc = Am + ((size_t)by * 128 + sRow) * HW + aKkSwz * 8;
    const float*    xSrc = x + ((size_t)bx * 128 + sRow) * HW + sKk * 8;
    const int xDstByte = ((sRow * 128 + sKk * 16) ^ ((sRow & 7) << 4));  // + i*4096

    f32x4 acc[4][4] = {};
    f32x4 xr0, xr1, xr2, xr3, xr4, xr5, xr6, xr7;   // x staging regs (static names)

    char* As[2] = { lds,         lds + 32768 };
    char* Xs[2] = { lds + 16384, lds + 49152 };

    #define G1_ISSUE_X(kt)                                                        \
        { const float* p = xSrc + (kt);                                           \
          xr0 = *(const f32x4*)(p);                 xr1 = *(const f32x4*)(p + 4); \
          p += (size_t)32 * HW;                                                   \
          xr2 = *(const f32x4*)(p);                 xr3 = *(const f32x4*)(p + 4); \
          p += (size_t)32 * HW;                                                   \
          xr4 = *(const f32x4*)(p);                 xr5 = *(const f32x4*)(p + 4); \
          p += (size_t)32 * HW;                                                   \
          xr6 = *(const f32x4*)(p);                 xr7 = *(const f32x4*)(p + 4); }

    #define G1_GLOAD_A(kt, asBase)                                                \
        _Pragma("unroll")                                                         \
        for (int i = 0; i < 4; ++i)                                               \
            gload16(aSrc + (kt) + (size_t)i * 32 * HW, (asBase) + i * 4096 + t * 16);

    #define G1_WRITE_X(xsBase)                                                                   \
        { f16x8 h0 = { (_Float16)xr0[0], (_Float16)xr0[1], (_Float16)xr0[2], (_Float16)xr0[3],   \
                       (_Float16)xr1[0], (_Float16)xr1[1], (_Float16)xr1[2], (_Float16)xr1[3] }; \
          f16x8 h1 = { (_Float16)xr2[0], (_Float16)xr2[1], (_Float16)xr2[2], (_Float16)xr2[3],   \
                       (_Float16)xr3[0], (_Float16)xr3[1], (_Float16)xr3[2], (_Float16)xr3[3] }; \
          f16x8 h2 = { (_Float16)xr4[0], (_Float16)xr4[1], (_Float16)xr4[2], (_Float16)xr4[3],   \
                       (_Float16)xr5[0], (_Float16)xr5[1], (_Float16)xr5[2], (_Float16)xr5[3] }; \
          f16x8 h3 = { (_Float16)xr6[0], (_Float16)xr6[1], (_Float16)xr6[2], (_Float16)xr6[3],   \
                       (_Float16)xr7[0], (_Float16)xr7[1], (_Float16)xr7[2], (_Float16)xr7[3] }; \
          *(f16x8*)((xsBase) + 0 * 4096 + xDstByte) = h0;                         \
          *(f16x8*)((xsBase) + 1 * 4096 + xDstByte) = h1;                         \
          *(f16x8*)((xsBase) + 2 * 4096 + xDstByte) = h2;                         \
          *(f16x8*)((xsBase) + 3 * 4096 + xDstByte) = h3; }

    // prologue: stage tile 0 into buf 0
    G1_ISSUE_X(0)
    G1_GLOAD_A(0, As[0])
    G1_WRITE_X(Xs[0])
    __syncthreads();

    constexpr int NT = HW / 64;
    for (int kt_i = 0; kt_i < NT; ++kt_i) {
        const int cur = kt_i & 1;
        const bool more = (kt_i + 1) < NT;
        char* AsC = (cur ? As[1] : As[0]);
        char* XsC = (cur ? Xs[1] : Xs[0]);
        char* AsN = (cur ? As[0] : As[1]);
        char* XsN = (cur ? Xs[0] : Xs[1]);
        if (more) {
            G1_ISSUE_X((kt_i + 1) * 64)
            G1_GLOAD_A((kt_i + 1) * 64, AsN)
        }
        #pragma unroll
        for (int k2 = 0; k2 < 2; ++k2) {
            f16x8 af[4], bf[4];
            int kByte = k2 * 64 + (lane >> 4) * 16;
            #pragma unroll
            for (int mi = 0; mi < 4; ++mi) {
                int row = wm + mi * 16 + (lane & 15);
                af[mi] = *(const f16x8*)(AsC + ((row * 128 + kByte) ^ ((row & 7) << 4)));
            }
            #pragma unroll
            for (int ni = 0; ni < 4; ++ni) {
                int row = wn + ni * 16 + (lane & 15);
                bf[ni] = *(const f16x8*)(XsC + ((row * 128 + kByte) ^ ((row & 7) << 4)));
            }
            #pragma unroll
            for (int mi = 0; mi < 4; ++mi)
                #pragma unroll
                for (int ni = 0; ni < 4; ++ni)
                    acc[mi][ni] = __builtin_amdgcn_mfma_f32_16x16x32_f16(af[mi], bf[ni], acc[mi][ni], 0, 0, 0);
        }
        if (more) G1_WRITE_X(XsN)
        __syncthreads();
    }

    int row0 = by * 128 + wm + ((lane >> 4) << 2);
    int col0 = bx * 128 + wn + (lane & 15);
    #pragma unroll
    for (int mi = 0; mi < 4; ++mi)
        #pragma unroll
        for (int ni = 0; ni < 4; ++ni)
            #pragma unroll
            for (int r = 0; r < 4; ++r) {
                int gw = row0 + mi * 16 + r;
                int gc = col0 + ni * 16;
                int b = gc >> 8, c = gc & 255;
                temp[(size_t)b * (AW * CDIM) + (size_t)gw * CDIM + c] = (_Float16)acc[mi][ni][r];
            }
}

// ---------------- GEMM2 (dbuf 2-phase): out[b][w][d] = sum_c temp[b][w][c] * BmT[d][c] ----------------
__global__ __launch_bounds__(256) void gemm2_kernel(
        const _Float16* __restrict__ A, long aStride,
        const _Float16* __restrict__ B,
        float* __restrict__ outP, int M, int N, int K) {
    __shared__ __align__(16) char lds[65536];
    const int t = threadIdx.x;
    const int lane = t & 63;
    const int wave = t >> 6;
    const int wm = (wave >> 1) * 64;
    const int wn = (wave & 1) * 64;
    const int z = blockIdx.z;

    const int r0 = t >> 3;
    const int kk = t & 7;
    const int kkSwz = kk ^ (r0 & 7);

    const _Float16* aSrc = A + (size_t)z * aStride + ((size_t)blockIdx.y * 128 + r0) * K + kkSwz * 8;
    const _Float16* bSrc = B + ((size_t)blockIdx.x * 128 + r0) * K + kkSwz * 8;

    f32x4 acc[4][4] = {};

    #define G2_STAGE(kt, asB, bsB)                                                 \
        _Pragma("unroll")                                                          \
        for (int i = 0; i < 4; ++i)                                                \
            gload16(aSrc + (kt) + (size_t)i * 32 * K, (asB) + i * 4096 + t * 16);  \
        _Pragma("unroll")                                                          \
        for (int i = 0; i < 4; ++i)                                                \
            gload16(bSrc + (kt) + (size_t)i * 32 * K, (bsB) + i * 4096 + t * 16);

    G2_STAGE(0, lds, lds + 16384)
    __syncthreads();

    const int NT = K / 64;
    for (int kt_i = 0; kt_i < NT; ++kt_i) {
        const int cur = kt_i & 1;
        char* AsC = lds + (cur ? 32768 : 0);
        char* BsC = AsC + 16384;
        char* AsN = lds + (cur ? 0 : 32768);
        char* BsN = AsN + 16384;
        if (kt_i + 1 < NT) { G2_STAGE((kt_i + 1) * 64, AsN, BsN) }
        #pragma unroll
        for (int k2 = 0; k2 < 2; ++k2) {
            f16x8 af[4], bf[4];
            int kByte = k2 * 64 + (lane >> 4) * 16;
            #pragma unroll
            for (int mi = 0; mi < 4; ++mi) {
                int row = wm + mi * 16 + (lane & 15);
                af[mi] = *(const f16x8*)(AsC + ((row * 128 + kByte) ^ ((row & 7) << 4)));
            }
            #pragma unroll
            for (int ni = 0; ni < 4; ++ni) {
                int row = wn + ni * 16 + (lane & 15);
                bf[ni] = *(const f16x8*)(BsC + ((row * 128 + kByte) ^ ((row & 7) << 4)));
            }
            #pragma unroll
            for (int mi = 0; mi < 4; ++mi)
                #pragma unroll
                for (int ni = 0; ni < 4; ++ni)
                    acc[mi][ni] = __builtin_amdgcn_mfma_f32_16x16x32_f16(af[mi], bf[ni], acc[mi][ni], 0, 0, 0);
        }
        __syncthreads();
    }

    int row0 = blockIdx.y * 128 + wm + ((lane >> 4) << 2);
    int col0 = blockIdx.x * 128 + wn + (lane & 15);
    size_t outBase = (size_t)z * M * N;
    #pragma unroll
    for (int mi = 0; mi < 4; ++mi)
        #pragma unroll
        for (int ni = 0; ni < 4; ++ni)
            #pragma unroll
            for (int r = 0; r < 4; ++r)
                outP[outBase + (size_t)(row0 + mi * 16 + r) * N + col0 + ni * 16] = acc[mi][ni][r];
}

// NOTE on GEMM1 buffer swap correctness: iter t reads buf[t&1] and writes buf[(t+1)&1];
// the single end-of-iter __syncthreads() (which also drains vmcnt/lgkmcnt) orders
// "all reads of cur done" before iter t+1 overwrites cur — buffers disjoint, one barrier suffices.

// ---------------- launch ----------------
extern "C" void kernel_launch(void* const* d_in, const int* in_sizes, int n_in,
                              void* d_out, int out_size, void* d_ws, size_t ws_size,
                              hipStream_t stream) {
    const float* x     = (const float*)d_in[0];
    const float* A_ref = (const float*)d_in[1];
    const float* B_ref = (const float*)d_in[2];
    const float* sA    = (const float*)d_in[3];
    const float* sB    = (const float*)d_in[4];
    float* out = (float*)d_out;
    char* ws = (char*)d_ws;

    const int nA = AW * AH;  const unsigned jA = (unsigned)(nA / 2);
    const int nB = BW * BH;  const unsigned jB = (unsigned)(nB / 2);
    const int outElems = BATCH * AW * BH;  // 16,777,216 f32

    _Float16* Am     = (_Float16*)(ws + 0);          // [1024][4096] f16
    _Float16* BmT    = (_Float16*)(ws + 8388608);    // [512][256]  f16
    _Float16* temp   = (_Float16*)(ws + 8650752);    // [32][1024][256] f16
    unsigned* scratch= (unsigned*)(ws + 25427968);

    hipMemsetAsync(scratch, 0, MEMSET_U32 * 4, stream);

    // ---- mask pipeline (A and B halves via blockIdx.y) ----
    hist0_kernel<<<dim3(256, 2), 256, 0, stream>>>(sA, nA, sB, nB, scratch);
    hist1_kernel<<<dim3(256, 2), 256, 0, stream>>>(sA, nA, jA, sB, nB, jB, scratch);
    extract_kernel<<<dim3(256, 2), 256, 0, stream>>>(sA, nA, jA, sB, nB, jB, scratch);
    finalize_kernel<<<dim3(1, 2), 256, 0, stream>>>(scratch);
    apply_kernel<<<dim3(2048, 2), 256, 0, stream>>>(sA, A_ref, Am, out + outElems,
                                                    sB, B_ref, BmT, out + outElems + nA,
                                                    nA, nB, scratch);

    // ---- GEMM1 (merged batch, dbuf 2-phase, fused f32->f16 at staging, XCD-local x reuse) ----
    gemm1_kernel<<<512, 256, 0, stream>>>(Am, x, temp);

    // ---- GEMM2 (dbuf 2-phase) ----
    gemm2_kernel<<<dim3(BH / 128, AW / 128, BATCH), 256, 0, stream>>>(
        temp, (long)AW * CDIM, BmT, out, AW, BH, CDIM);
}

// Round 7
// 198.056 us; speedup vs baseline: 1.1371x; 1.1371x over previous
//
#include <hip/hip_runtime.h>

typedef _Float16 f16x8 __attribute__((ext_vector_type(8)));
typedef _Float16 f16x4 __attribute__((ext_vector_type(4)));
typedef float    f32x4 __attribute__((ext_vector_type(4)));

static constexpr int BATCH = 32;
static constexpr int CDIM  = 256;    // C
static constexpr int HW    = 4096;   // h (= A_H = K of GEMM1)
static constexpr int AW    = 1024;   // A rows (w)
static constexpr int AH    = 4096;   // A cols (h)
static constexpr int BW    = 256;    // B rows (c)
static constexpr int BH    = 512;    // B cols (d)
static constexpr int CAND_CAP = 8192;

// scratch u32 layout
// 0     histA0[4096]   4096  histA1[4096]
// 8192  histB0[4096]   12288 histB1[4096]
// 16384 selA[8]  ([3]=target2 [4]=vcut [5]=cutIdx [6]=candCount)
// 16392 selB[8]
// 16400 candBitsA[8192]  24592 candIdxA[8192]
// 32784 candBitsB[8192]  40976 candIdxB[8192]
static constexpr int MEMSET_U32 = 16400;

__device__ __forceinline__ void gload16(const void* g, void* l) {
    __builtin_amdgcn_global_load_lds((const __attribute__((address_space(1))) void*)g,
                                     (__attribute__((address_space(3))) void*)l, 16, 0, 0);
}

// every block computes the same select result from a global 4096-bin histogram.
__device__ void select_bin_inline(const unsigned* __restrict__ hist, unsigned target,
                                  unsigned* shp /*[256]*/, unsigned* res /*[2]*/) {
    const int t = threadIdx.x;
    unsigned sum = 0;
    #pragma unroll
    for (int k = 0; k < 16; ++k) sum += hist[t * 16 + k];
    shp[t] = sum;
    __syncthreads();
    if (t == 0) {
        unsigned c = 0; int k = 0;
        while (c + shp[k] <= target) { c += shp[k]; ++k; }
        int b = k * 16;
        while (true) { unsigned h = hist[b]; if (target < c + h) break; c += h; ++b; }
        res[0] = (unsigned)b; res[1] = c;
    }
    __syncthreads();
}

// ---------------- pass 0: hist of key>>19 (12 bits) + fused x f32->f16 conversion ----------------
// blockIdx.y: 0 = hist(sA), 1 = hist(sB), 2 = stream-convert x to xf16 (rides the same dispatch).
__global__ void hist0_cvt_kernel(const float* __restrict__ sA, int nA,
                                 const float* __restrict__ sB, int nB,
                                 const float* __restrict__ x, _Float16* __restrict__ xf, int nx8,
                                 unsigned* __restrict__ scratch) {
    __shared__ unsigned lh[4][4096];
    const int y = blockIdx.y;
    const int t = threadIdx.x;
    if (y == 2) {
        int i = blockIdx.x * 256 + t;
        int stride = gridDim.x * 256;
        for (; i < nx8; i += stride) {
            f32x4 v0 = reinterpret_cast<const f32x4*>(x)[i * 2];
            f32x4 v1 = reinterpret_cast<const f32x4*>(x)[i * 2 + 1];
            f16x8 h = { (_Float16)v0[0], (_Float16)v0[1], (_Float16)v0[2], (_Float16)v0[3],
                        (_Float16)v1[0], (_Float16)v1[1], (_Float16)v1[2], (_Float16)v1[3] };
            reinterpret_cast<f16x8*>(xf)[i] = h;
        }
        return;
    }
    const float* s = y ? sB : sA;
    const int n4 = (y ? nB : nA) >> 2;
    unsigned* hist = scratch + (y ? 8192 : 0);
    const int wave = t >> 6;
    for (int i = t; i < 4 * 4096; i += 256) ((unsigned*)lh)[i] = 0;
    __syncthreads();
    for (int i = blockIdx.x * 256 + t; i < n4; i += gridDim.x * 256) {
        float4 v = reinterpret_cast<const float4*>(s)[i];
        atomicAdd(&lh[wave][(__float_as_uint(v.x) & 0x7fffffffu) >> 19], 1u);
        atomicAdd(&lh[wave][(__float_as_uint(v.y) & 0x7fffffffu) >> 19], 1u);
        atomicAdd(&lh[wave][(__float_as_uint(v.z) & 0x7fffffffu) >> 19], 1u);
        atomicAdd(&lh[wave][(__float_as_uint(v.w) & 0x7fffffffu) >> 19], 1u);
    }
    __syncthreads();
    for (int b = t; b < 4096; b += 256) {
        unsigned v = lh[0][b] + lh[1][b] + lh[2][b] + lh[3][b];
        if (v) atomicAdd(&hist[b], v);
    }
}

// ---------------- pass 1: inline select0, hist of (key>>7)&4095 among prefix matches ----------------
__global__ void hist1_kernel(const float* __restrict__ sA, int nA, unsigned jA,
                             const float* __restrict__ sB, int nB, unsigned jB,
                             unsigned* __restrict__ scratch) {
    __shared__ unsigned lh[4][4096];
    __shared__ unsigned shp[256];
    __shared__ unsigned res[2];
    const int y = blockIdx.y;
    const float* s = y ? sB : sA;
    const int n4 = (y ? nB : nA) >> 2;
    const unsigned j = y ? jB : jA;
    const unsigned* hist0 = scratch + (y ? 8192 : 0);
    unsigned* hist1 = scratch + 4096 + (y ? 8192 : 0);
    const int t = threadIdx.x;
    const int wave = t >> 6;
    for (int i = t; i < 4 * 4096; i += 256) ((unsigned*)lh)[i] = 0;
    select_bin_inline(hist0, j, shp, res);       // includes syncthreads
    const unsigned bin0 = res[0];
    for (int i = blockIdx.x * 256 + t; i < n4; i += gridDim.x * 256) {
        float4 v = reinterpret_cast<const float4*>(s)[i];
        unsigned k0 = __float_as_uint(v.x) & 0x7fffffffu;
        unsigned k1 = __float_as_uint(v.y) & 0x7fffffffu;
        unsigned k2 = __float_as_uint(v.z) & 0x7fffffffu;
        unsigned k3 = __float_as_uint(v.w) & 0x7fffffffu;
        if ((k0 >> 19) == bin0) atomicAdd(&lh[wave][(k0 >> 7) & 4095], 1u);
        if ((k1 >> 19) == bin0) atomicAdd(&lh[wave][(k1 >> 7) & 4095], 1u);
        if ((k2 >> 19) == bin0) atomicAdd(&lh[wave][(k2 >> 7) & 4095], 1u);
        if ((k3 >> 19) == bin0) atomicAdd(&lh[wave][(k3 >> 7) & 4095], 1u);
    }
    __syncthreads();
    for (int b = t; b < 4096; b += 256) {
        unsigned v = lh[0][b] + lh[1][b] + lh[2][b] + lh[3][b];
        if (v) atomicAdd(&hist1[b], v);
    }
}

// ---------------- extract: inline select0+select1, gather candidates with 24-bit prefix ----------------
__global__ void extract_kernel(const float* __restrict__ sA, int nA, unsigned jA,
                               const float* __restrict__ sB, int nB, unsigned jB,
                               unsigned* __restrict__ scratch) {
    __shared__ unsigned shp[256];
    __shared__ unsigned res0[2], res1[2];
    const int y = blockIdx.y;
    const float* s = y ? sB : sA;
    const int n4 = (y ? nB : nA) >> 2;
    const unsigned j = y ? jB : jA;
    const unsigned* hist0 = scratch + (y ? 8192 : 0);
    const unsigned* hist1 = scratch + 4096 + (y ? 8192 : 0);
    unsigned* sel = scratch + 16384 + y * 8;
    unsigned* candBits = scratch + (y ? 32784 : 16400);
    unsigned* candIdx  = candBits + CAND_CAP;
    const int t = threadIdx.x;
    select_bin_inline(hist0, j, shp, res0);
    select_bin_inline(hist1, j - res0[1], shp, res1);
    const unsigned pref = (res0[0] << 12) | res1[0];
    const unsigned base2 = res0[1] + res1[1];
    if (blockIdx.x == 0 && t == 0) sel[3] = j - base2;   // rank within candidate set
    for (int i = blockIdx.x * 256 + t; i < n4; i += gridDim.x * 256) {
        float4 v = reinterpret_cast<const float4*>(s)[i];
        #pragma unroll
        for (int k = 0; k < 4; ++k) {
            unsigned bits = __float_as_uint(k == 0 ? v.x : k == 1 ? v.y : k == 2 ? v.z : v.w) & 0x7fffffffu;
            if ((bits >> 7) == pref) {
                unsigned p = atomicAdd(&sel[6], 1u);
                if (p < CAND_CAP) { candBits[p] = bits; candIdx[p] = (unsigned)(i * 4 + k); }
            }
        }
    }
}

// ---------------- finalize: exact (value, index)-lexicographic rank among candidates ----------------
__global__ void finalize_kernel(unsigned* __restrict__ scratch) {
    __shared__ unsigned sb[CAND_CAP];
    __shared__ unsigned si[CAND_CAP];
    const int y = blockIdx.y;
    unsigned* sel = scratch + 16384 + y * 8;
    const unsigned* candBits = scratch + (y ? 32784 : 16400);
    const unsigned* candIdx  = candBits + CAND_CAP;
    const int t = threadIdx.x;
    unsigned cnt = sel[6]; if (cnt > CAND_CAP) cnt = CAND_CAP;
    const unsigned target = sel[3];
    for (unsigned c = t; c < cnt; c += 256) { sb[c] = candBits[c]; si[c] = candIdx[c]; }
    __syncthreads();
    for (unsigned c = t; c < cnt; c += 256) {
        unsigned b = sb[c], ix = si[c];
        unsigned r = 0;
        for (unsigned q = 0; q < cnt; ++q)
            r += (sb[q] < b) || (sb[q] == b && si[q] < ix);
        if (r == target) { sel[4] = b; sel[5] = ix; }
    }
}

// ---------------- apply: branchless mask + masked-f16 write + f32 pass-through copy ----------------
__global__ void apply_kernel(const float* __restrict__ sA, const float* __restrict__ wA,
                             _Float16* __restrict__ Am, float* __restrict__ wcopyA,
                             const float* __restrict__ sB, const float* __restrict__ wB,
                             _Float16* __restrict__ BmT, float* __restrict__ wcopyB,
                             int nA, int nB, const unsigned* __restrict__ scratch) {
    const int y = blockIdx.y;
    const float* s = y ? sB : sA;
    const float* w = y ? wB : wA;
    float* wcopy = y ? wcopyB : wcopyA;
    const int n4 = (y ? nB : nA) >> 2;
    const unsigned* sel = scratch + 16384 + y * 8;
    const unsigned vcut = sel[4], cutIdx = sel[5];
    const int t = threadIdx.x;
    for (int i = blockIdx.x * 256 + t; i < n4; i += gridDim.x * 256) {
        float4 sv = reinterpret_cast<const float4*>(s)[i];
        float4 wv = reinterpret_cast<const float4*>(w)[i];
        reinterpret_cast<float4*>(wcopy)[i] = wv;
        unsigned idx0 = (unsigned)i * 4;
        float m[4];
        #pragma unroll
        for (int k = 0; k < 4; ++k) {
            unsigned bits = __float_as_uint(k == 0 ? sv.x : k == 1 ? sv.y : k == 2 ? sv.z : sv.w) & 0x7fffffffu;
            bool keep = (bits > vcut) || (bits == vcut && (idx0 + k) >= cutIdx);
            m[k] = keep ? 1.0f : 0.0f;
        }
        if (!y) {
            f16x4 o = { (_Float16)(wv.x * m[0]), (_Float16)(wv.y * m[1]),
                        (_Float16)(wv.z * m[2]), (_Float16)(wv.w * m[3]) };
            *reinterpret_cast<f16x4*>(Am + idx0) = o;
        } else {
            int c = (int)(idx0 >> 9);           // row of B_ref [256][512]
            int d = (int)(idx0 & 511);
            BmT[(size_t)(d + 0) * BW + c] = (_Float16)(wv.x * m[0]);
            BmT[(size_t)(d + 1) * BW + c] = (_Float16)(wv.y * m[1]);
            BmT[(size_t)(d + 2) * BW + c] = (_Float16)(wv.z * m[2]);
            BmT[(size_t)(d + 3) * BW + c] = (_Float16)(wv.w * m[3]);
        }
    }
}

// ---------------- GEMM1 (m97-exact structure): temp[b][w][c] = sum_h Am[w][h] * xf[(b,c)][h] ----------------
// Both operands f16 via global_load_lds (pre-swizzled source, linear LDS dest), single 32KB buffer,
// 2-barrier K-loop. 128x128 tile, 4 waves (2x2), 4x4 mfma_f32_16x16x32_f16 per wave.
// XCD-local x reuse: XCD k owns bx in [8k,8k+8); all 8 by per bx run on that XCD.
__global__ __launch_bounds__(256) void gemm1_kernel(
        const _Float16* __restrict__ Am,   // [1024][4096] f16
        const _Float16* __restrict__ xf,   // [8192][4096] f16 ((b,c) major)
        _Float16* __restrict__ temp) {     // [32][1024][256] f16
    __shared__ __align__(16) char lds[32768];
    char* As = lds;
    char* Xs = lds + 16384;
    const int t = threadIdx.x;
    const int lane = t & 63;
    const int wave = t >> 6;
    const int wm = (wave >> 1) * 64;
    const int wn = (wave & 1) * 64;

    const int xcd = blockIdx.x & 7;
    const int seq = blockIdx.x >> 3;
    const int bx = xcd * 8 + (seq >> 3);   // N-tile 0..63 (b,c)
    const int by = seq & 7;                // M-tile 0..7  (w)

    // staging: chunk c = i*256+t; row = c>>3 (i*32 + t>>3), phys chunk = t&7,
    // logical chunk = (t&7) ^ (row&7)  [inverse-swizzled source, linear LDS dest]
    const int sRow = t >> 3;
    const int sKk  = (t & 7) ^ (sRow & 7);
    const _Float16* aSrc = Am + ((size_t)by * 128 + sRow) * HW + sKk * 8;
    const _Float16* xSrc = xf + ((size_t)bx * 128 + sRow) * HW + sKk * 8;

    f32x4 acc[4][4] = {};

    for (int kt = 0; kt < HW; kt += 64) {
        __syncthreads();
        #pragma unroll
        for (int i = 0; i < 4; ++i)
            gload16(aSrc + kt + (size_t)i * 32 * HW, As + i * 4096 + t * 16);
        #pragma unroll
        for (int i = 0; i < 4; ++i)
            gload16(xSrc + kt + (size_t)i * 32 * HW, Xs + i * 4096 + t * 16);
        __syncthreads();
        #pragma unroll
        for (int k2 = 0; k2 < 2; ++k2) {
            f16x8 af[4], bf[4];
            int kByte = k2 * 64 + (lane >> 4) * 16;
            #pragma unroll
            for (int mi = 0; mi < 4; ++mi) {
                int row = wm + mi * 16 + (lane & 15);
                af[mi] = *(const f16x8*)(As + ((row * 128 + kByte) ^ ((row & 7) << 4)));
            }
            #pragma unroll
            for (int ni = 0; ni < 4; ++ni) {
                int row = wn + ni * 16 + (lane & 15);
                bf[ni] = *(const f16x8*)(Xs + ((row * 128 + kByte) ^ ((row & 7) << 4)));
            }
            #pragma unroll
            for (int mi = 0; mi < 4; ++mi)
                #pragma unroll
                for (int ni = 0; ni < 4; ++ni)
                    acc[mi][ni] = __builtin_amdgcn_mfma_f32_16x16x32_f16(af[mi], bf[ni], acc[mi][ni], 0, 0, 0);
        }
    }

    int row0 = by * 128 + wm + ((lane >> 4) << 2);
    int col0 = bx * 128 + wn + (lane & 15);
    #pragma unroll
    for (int mi = 0; mi < 4; ++mi)
        #pragma unroll
        for (int ni = 0; ni < 4; ++ni)
            #pragma unroll
            for (int r = 0; r < 4; ++r) {
                int gw = row0 + mi * 16 + r;
                int gc = col0 + ni * 16;
                int b = gc >> 8, c = gc & 255;
                temp[(size_t)b * (AW * CDIM) + (size_t)gw * CDIM + c] = (_Float16)acc[mi][ni][r];
            }
}

// ---------------- GEMM2 (dbuf 2-phase): out[b][w][d] = sum_c temp[b][w][c] * BmT[d][c] ----------------
__global__ __launch_bounds__(256) void gemm2_kernel(
        const _Float16* __restrict__ A, long aStride,
        const _Float16* __restrict__ B,
        float* __restrict__ outP, int M, int N, int K) {
    __shared__ __align__(16) char lds[65536];
    const int t = threadIdx.x;
    const int lane = t & 63;
    const int wave = t >> 6;
    const int wm = (wave >> 1) * 64;
    const int wn = (wave & 1) * 64;
    const int z = blockIdx.z;

    const int r0 = t >> 3;
    const int kk = t & 7;
    const int kkSwz = kk ^ (r0 & 7);

    const _Float16* aSrc = A + (size_t)z * aStride + ((size_t)blockIdx.y * 128 + r0) * K + kkSwz * 8;
    const _Float16* bSrc = B + ((size_t)blockIdx.x * 128 + r0) * K + kkSwz * 8;

    f32x4 acc[4][4] = {};

    #define G2_STAGE(kt, asB, bsB)                                                 \
        _Pragma("unroll")                                                          \
        for (int i = 0; i < 4; ++i)                                                \
            gload16(aSrc + (kt) + (size_t)i * 32 * K, (asB) + i * 4096 + t * 16);  \
        _Pragma("unroll")                                                          \
        for (int i = 0; i < 4; ++i)                                                \
            gload16(bSrc + (kt) + (size_t)i * 32 * K, (bsB) + i * 4096 + t * 16);

    G2_STAGE(0, lds, lds + 16384)
    __syncthreads();

    const int NT = K / 64;
    for (int kt_i = 0; kt_i < NT; ++kt_i) {
        const int cur = kt_i & 1;
        char* AsC = lds + (cur ? 32768 : 0);
        char* BsC = AsC + 16384;
        char* AsN = lds + (cur ? 0 : 32768);
        char* BsN = AsN + 16384;
        // NOTE: buffers alternate; first iter computes on buf0 which was staged in prologue.
        if (kt_i == 0) { AsC = lds; BsC = lds + 16384; AsN = lds + 32768; BsN = lds + 49152; }
        if (kt_i + 1 < NT) { G2_STAGE((kt_i + 1) * 64, AsN, BsN) }
        #pragma unroll
        for (int k2 = 0; k2 < 2; ++k2) {
            f16x8 af[4], bf[4];
            int kByte = k2 * 64 + (lane >> 4) * 16;
            #pragma unroll
            for (int mi = 0; mi < 4; ++mi) {
                int row = wm + mi * 16 + (lane & 15);
                af[mi] = *(const f16x8*)(AsC + ((row * 128 + kByte) ^ ((row & 7) << 4)));
            }
            #pragma unroll
            for (int ni = 0; ni < 4; ++ni) {
                int row = wn + ni * 16 + (lane & 15);
                bf[ni] = *(const f16x8*)(BsC + ((row * 128 + kByte) ^ ((row & 7) << 4)));
            }
            #pragma unroll
            for (int mi = 0; mi < 4; ++mi)
                #pragma unroll
                for (int ni = 0; ni < 4; ++ni)
                    acc[mi][ni] = __builtin_amdgcn_mfma_f32_16x16x32_f16(af[mi], bf[ni], acc[mi][ni], 0, 0, 0);
        }
        __syncthreads();
    }

    int row0 = blockIdx.y * 128 + wm + ((lane >> 4) << 2);
    int col0 = blockIdx.x * 128 + wn + (lane & 15);
    size_t outBase = (size_t)z * M * N;
    #pragma unroll
    for (int mi = 0; mi < 4; ++mi)
        #pragma unroll
        for (int ni = 0; ni < 4; ++ni)
            #pragma unroll
            for (int r = 0; r < 4; ++r)
                outP[outBase + (size_t)(row0 + mi * 16 + r) * N + col0 + ni * 16] = acc[mi][ni][r];
}

// ---------------- launch ----------------
extern "C" void kernel_launch(void* const* d_in, const int* in_sizes, int n_in,
                              void* d_out, int out_size, void* d_ws, size_t ws_size,
                              hipStream_t stream) {
    const float* x     = (const float*)d_in[0];
    const float* A_ref = (const float*)d_in[1];
    const float* B_ref = (const float*)d_in[2];
    const float* sA    = (const float*)d_in[3];
    const float* sB    = (const float*)d_in[4];
    float* out = (float*)d_out;
    char* ws = (char*)d_ws;

    const int nA = AW * AH;  const unsigned jA = (unsigned)(nA / 2);
    const int nB = BW * BH;  const unsigned jB = (unsigned)(nB / 2);
    const int nx8 = (BATCH * CDIM * HW) / 8;   // 4,194,304 chunks of 8 f32
    const int outElems = BATCH * AW * BH;      // 16,777,216 f32

    _Float16* Am     = (_Float16*)(ws + 0);          // [1024][4096] f16
    _Float16* BmT    = (_Float16*)(ws + 8388608);    // [512][256]  f16
    _Float16* temp   = (_Float16*)(ws + 8650752);    // [32][1024][256] f16
    unsigned* scratch= (unsigned*)(ws + 25427968);

    // x (f16) overlays the d_out "out" region (exactly 67.1 MB; GEMM2 overwrites it at the end)
    _Float16* xf16 = (_Float16*)d_out;

    hipMemsetAsync(scratch, 0, MEMSET_U32 * 4, stream);

    // ---- mask pipeline + fused x conversion ----
    hist0_cvt_kernel<<<dim3(256, 3), 256, 0, stream>>>(sA, nA, sB, nB, x, xf16, nx8, scratch);
    hist1_kernel<<<dim3(256, 2), 256, 0, stream>>>(sA, nA, jA, sB, nB, jB, scratch);
    extract_kernel<<<dim3(256, 2), 256, 0, stream>>>(sA, nA, jA, sB, nB, jB, scratch);
    finalize_kernel<<<dim3(1, 2), 256, 0, stream>>>(scratch);
    apply_kernel<<<dim3(2048, 2), 256, 0, stream>>>(sA, A_ref, Am, out + outElems,
                                                    sB, B_ref, BmT, out + outElems + nA,
                                                    nA, nB, scratch);

    // ---- GEMM1 (m97-exact, both operands f16 gload_lds, XCD-local x reuse) ----
    gemm1_kernel<<<512, 256, 0, stream>>>(Am, xf16, temp);

    // ---- GEMM2 (dbuf 2-phase) ----
    gemm2_kernel<<<dim3(BH / 128, AW / 128, BATCH), 256, 0, stream>>>(
        temp, (long)AW * CDIM, BmT, out, AW, BH, CDIM);
}